// Round 1
// baseline (205.898 us; speedup 1.0000x reference)
//
#include <hip/hip_runtime.h>
#include <hip/hip_bf16.h>
#include <cstdint>
#include <cstddef>

// SelfAttentionV2: x[4096,1024] fp32; Wq/Wk/Wv [1024,1024] fp32.
// out = softmax(causal((x Wq^T)(x Wk^T)^T / 32)) @ (x Wv^T), fp32 out.
//
// Pipeline (all bf16 MFMA):
//   cvt: x->xb bf16, W->Wcat bf16 (Wq scaled by 1/32)
//   gemm_qkv: C[4096,3072] = xb @ Wcat^T -> Qb,Kb row-major bf16; V stored transposed (Vt[1024][4096])
//   gemm_qkt: S = Qb @ Kb^T, lower-triangle tiles only, diag masked with -inf, bf16
//   softmax:  row softmax over causal prefix, in place, bf16 P
//   gemm_pv:  out = P @ Vt^T (B^T-form GEMM), causal-aware K loop, fp32 out

#define SEQQ 4096
#define DDIM 1024

typedef __bf16 bf16x8 __attribute__((ext_vector_type(8)));
typedef float f32x4 __attribute__((ext_vector_type(4)));

__device__ __forceinline__ unsigned short f2bf(float f) {
  unsigned int u = __builtin_bit_cast(unsigned int, f);
  unsigned int r = u + 0x7FFFu + ((u >> 16) & 1u);  // RNE; -inf stays -inf
  return (unsigned short)(r >> 16);
}

__device__ __forceinline__ float bf2f(unsigned short b) {
  return __builtin_bit_cast(float, (unsigned int)b << 16);
}

__device__ __forceinline__ void gload_lds16(const void* g, void* lds) {
  __builtin_amdgcn_global_load_lds(
      (__attribute__((address_space(1))) void*)(uintptr_t)g,
      (__attribute__((address_space(3))) void*)(uintptr_t)lds, 16, 0, 0);
}

// ---- fp32 -> bf16 conversion with optional scale ----
__global__ __launch_bounds__(256) void cvt_kernel(const float* __restrict__ src,
                                                  unsigned short* __restrict__ dst,
                                                  int n, float scale) {
  int i = (blockIdx.x * 256 + threadIdx.x) * 4;
  if (i >= n) return;
  const float4 v = *reinterpret_cast<const float4*>(src + i);
  ushort4 o;
  o.x = f2bf(v.x * scale);
  o.y = f2bf(v.y * scale);
  o.z = f2bf(v.z * scale);
  o.w = f2bf(v.w * scale);
  *reinterpret_cast<ushort4*>(dst + i) = o;
}

// ---- shared GEMM building blocks (128x128 tile, BK=32, 4 waves) ----
// LDS tile: 128 rows x 32 bf16 (64B/row), st_16x32 XOR swizzle:
//   byte ^= ((row>>3)&1)<<5, applied to source on stage and to addr on read.

__device__ __forceinline__ void stage128x32(const unsigned short* gtile, size_t ld /*elems*/,
                                            unsigned short* lds, int wave, int lane) {
#pragma unroll
  for (int i = 0; i < 2; ++i) {
    const int c = wave * 2 + i;                 // chunk 0..7, 16 rows each
    const int row = c * 16 + (lane >> 2);
    const int kb = ((lane & 3) * 16) ^ (((row >> 3) & 1) << 5);  // inverse-swizzled source
    const char* src = (const char*)gtile + (size_t)row * (ld * 2) + kb;
    char* dst = (char*)lds + c * 1024;          // wave-uniform base; HW adds lane*16
    gload_lds16(src, dst);
  }
}

__device__ __forceinline__ void load_frags(const unsigned short* lds, int wrow, int lane,
                                           bf16x8 f[4]) {
  const int r0 = wrow + (lane & 15);
  const int kb = (lane >> 4) * 16;
#pragma unroll
  for (int m = 0; m < 4; ++m) {
    int off = ((r0 + m * 16) << 6) + kb;        // row*64 + kbyte
    off ^= ((off >> 9) & 1) << 5;               // swizzled read
    f[m] = *reinterpret_cast<const bf16x8*>((const char*)lds + off);
  }
}

#define GEMM_PREAMBLE()                                        \
  __shared__ unsigned short As[128 * 32] __attribute__((aligned(16))); \
  __shared__ unsigned short Bs[128 * 32] __attribute__((aligned(16))); \
  const int tid = threadIdx.x;                                 \
  const int wave = tid >> 6, lane = tid & 63;                  \
  const int wr = (wave >> 1) * 64, wc = (wave & 1) * 64;       \
  f32x4 acc[4][4] = {};

#define GEMM_KSTEP(Aptr, lda, Bptr, ldb)                       \
  do {                                                         \
    stage128x32((Aptr), (lda), As, wave, lane);                \
    stage128x32((Bptr), (ldb), Bs, wave, lane);                \
    __syncthreads();                                           \
    bf16x8 a[4], b[4];                                         \
    load_frags(As, wr, lane, a);                               \
    load_frags(Bs, wc, lane, b);                               \
    _Pragma("unroll")                                          \
    for (int m = 0; m < 4; ++m)                                \
      _Pragma("unroll")                                        \
      for (int n = 0; n < 4; ++n)                              \
        acc[m][n] = __builtin_amdgcn_mfma_f32_16x16x32_bf16(   \
            a[m], b[n], acc[m][n], 0, 0, 0);                   \
    __syncthreads();                                           \
  } while (0)

// ---- QKV: C[4096,3072] = xb @ Wcat^T; Q,K row-major; V transposed ----
__global__ __launch_bounds__(256) void gemm_qkv(const unsigned short* __restrict__ X,
                                                const unsigned short* __restrict__ W,
                                                unsigned short* __restrict__ Qb,
                                                unsigned short* __restrict__ Kb,
                                                unsigned short* __restrict__ Vt) {
  GEMM_PREAMBLE();
  const int brow = blockIdx.y * 128, bcol = blockIdx.x * 128;
  for (int k0 = 0; k0 < DDIM; k0 += 32) {
    GEMM_KSTEP(X + (size_t)brow * DDIM + k0, DDIM,
               W + (size_t)bcol * DDIM + k0, DDIM);
  }
  const int region = bcol >> 10;  // 0=Q 1=K 2=V
  const int lcol = bcol & 1023;
  const int c0 = wc + (lane & 15);
  const int r0 = wr + ((lane >> 4) << 2);
  if (region < 2) {
    unsigned short* dst = (region == 0) ? Qb : Kb;
#pragma unroll
    for (int m = 0; m < 4; ++m) {
      const int r = brow + r0 + m * 16;
#pragma unroll
      for (int n = 0; n < 4; ++n) {
        const int c = lcol + c0 + n * 16;
#pragma unroll
        for (int j = 0; j < 4; ++j)
          dst[(size_t)(r + j) * DDIM + c] = f2bf(acc[m][n][j]);
      }
    }
  } else {
#pragma unroll
    for (int m = 0; m < 4; ++m) {
      const int r = brow + r0 + m * 16;
#pragma unroll
      for (int n = 0; n < 4; ++n) {
        const int c = lcol + c0 + n * 16;
        ushort4 pk;
        pk.x = f2bf(acc[m][n][0]);
        pk.y = f2bf(acc[m][n][1]);
        pk.z = f2bf(acc[m][n][2]);
        pk.w = f2bf(acc[m][n][3]);
        *reinterpret_cast<ushort4*>(Vt + (size_t)c * SEQQ + r) = pk;
      }
    }
  }
}

// ---- QK^T: S = Qb @ Kb^T, lower-triangle tiles, causal mask on diag ----
__global__ __launch_bounds__(256) void gemm_qkt(const unsigned short* __restrict__ Qb,
                                                const unsigned short* __restrict__ Kb,
                                                unsigned short* __restrict__ S) {
  const int bi = blockIdx.y, bj = blockIdx.x;
  if (bj > bi) return;  // upper-triangle tiles never computed nor read
  GEMM_PREAMBLE();
  const int brow = bi * 128, bcol = bj * 128;
  for (int k0 = 0; k0 < DDIM; k0 += 32) {
    GEMM_KSTEP(Qb + (size_t)brow * DDIM + k0, DDIM,
               Kb + (size_t)bcol * DDIM + k0, DDIM);
  }
  const int c0 = wc + (lane & 15);
  const int r0 = wr + ((lane >> 4) << 2);
#pragma unroll
  for (int m = 0; m < 4; ++m) {
    const int r = brow + r0 + m * 16;
#pragma unroll
    for (int n = 0; n < 4; ++n) {
      const int c = bcol + c0 + n * 16;
#pragma unroll
      for (int j = 0; j < 4; ++j) {
        unsigned short o = (c > r + j) ? (unsigned short)0xFF80  // -inf bf16
                                       : f2bf(acc[m][n][j]);
        S[(size_t)(r + j) * SEQQ + c] = o;
      }
    }
  }
}

// ---- row softmax over causal prefix, in place ----
__global__ __launch_bounds__(256) void softmax_causal(unsigned short* __restrict__ S) {
  const int row = blockIdx.x;
  const int L = ((row >> 7) + 1) << 7;  // multiple of 128 covering row+1
  unsigned short* Srow = S + (size_t)row * SEQQ;
  __shared__ float red[4];
  const int tid = threadIdx.x;
  const int lane = tid & 63, wave = tid >> 6;

  float x[16];
  bool have[2];
  float m = -3.0e38f;
#pragma unroll
  for (int it = 0; it < 2; ++it) {
    const int j = tid * 8 + it * 2048;
    have[it] = (j < L);
    if (have[it]) {
      const uint4 v = *reinterpret_cast<const uint4*>(Srow + j);
      const unsigned u[4] = {v.x, v.y, v.z, v.w};
#pragma unroll
      for (int q = 0; q < 4; ++q) {
        x[it * 8 + q * 2] = __builtin_bit_cast(float, u[q] << 16);
        x[it * 8 + q * 2 + 1] = __builtin_bit_cast(float, u[q] & 0xFFFF0000u);
      }
#pragma unroll
      for (int q = 0; q < 8; ++q) m = fmaxf(m, x[it * 8 + q]);
    }
  }
#pragma unroll
  for (int o = 32; o; o >>= 1) m = fmaxf(m, __shfl_xor(m, o));
  if (lane == 0) red[wave] = m;
  __syncthreads();
  m = fmaxf(fmaxf(red[0], red[1]), fmaxf(red[2], red[3]));
  __syncthreads();

  float sum = 0.f;
#pragma unroll
  for (int it = 0; it < 2; ++it)
    if (have[it]) {
#pragma unroll
      for (int q = 0; q < 8; ++q) {
        x[it * 8 + q] = __expf(x[it * 8 + q] - m);  // exp(-inf)=0 for masked
        sum += x[it * 8 + q];
      }
    }
#pragma unroll
  for (int o = 32; o; o >>= 1) sum += __shfl_xor(sum, o);
  if (lane == 0) red[wave] = sum;
  __syncthreads();
  sum = red[0] + red[1] + red[2] + red[3];
  const float inv = 1.0f / sum;

#pragma unroll
  for (int it = 0; it < 2; ++it)
    if (have[it]) {
      const int j = tid * 8 + it * 2048;
      unsigned u[4];
#pragma unroll
      for (int q = 0; q < 4; ++q) {
        u[q] = (unsigned)f2bf(x[it * 8 + q * 2] * inv) |
               ((unsigned)f2bf(x[it * 8 + q * 2 + 1] * inv) << 16);
      }
      *reinterpret_cast<uint4*>(Srow + j) = make_uint4(u[0], u[1], u[2], u[3]);
    }
}

// ---- PV: out[4096,1024] = P @ Vt^T, causal-aware K loop, fp32 out ----
__global__ __launch_bounds__(256) void gemm_pv(const unsigned short* __restrict__ P,
                                               const unsigned short* __restrict__ Vt,
                                               float* __restrict__ O) {
  GEMM_PREAMBLE();
  const int bi = blockIdx.y, bj = blockIdx.x;
  const int brow = bi * 128, bcol = bj * 128;
  const int kend = (bi + 1) * 128;
  for (int k0 = 0; k0 < kend; k0 += 32) {
    GEMM_KSTEP(P + (size_t)brow * SEQQ + k0, SEQQ,
               Vt + (size_t)bcol * SEQQ + k0, SEQQ);
  }
  const int c0 = wc + (lane & 15);
  const int r0 = wr + ((lane >> 4) << 2);
#pragma unroll
  for (int m = 0; m < 4; ++m) {
    const int r = brow + r0 + m * 16;
#pragma unroll
    for (int n = 0; n < 4; ++n) {
      const int c = bcol + c0 + n * 16;
#pragma unroll
      for (int j = 0; j < 4; ++j)
        O[(size_t)(r + j) * DDIM + c] = acc[m][n][j];
    }
  }
}

extern "C" void kernel_launch(void* const* d_in, const int* in_sizes, int n_in,
                              void* d_out, int out_size, void* d_ws, size_t ws_size,
                              hipStream_t stream) {
  (void)in_sizes; (void)n_in; (void)out_size; (void)ws_size;
  const float* x = (const float*)d_in[0];
  const float* Wq = (const float*)d_in[1];
  const float* Wk = (const float*)d_in[2];
  const float* Wv = (const float*)d_in[3];
  float* out = (float*)d_out;

  char* ws = (char*)d_ws;
  unsigned short* xb   = (unsigned short*)(ws);                        //  8 MB [4096,1024]
  unsigned short* Wcat = (unsigned short*)(ws + ((size_t)8 << 20));    //  6 MB [3072,1024]
  unsigned short* Qb   = (unsigned short*)(ws + ((size_t)14 << 20));   //  8 MB [4096,1024]
  unsigned short* Kb   = (unsigned short*)(ws + ((size_t)22 << 20));   //  8 MB [4096,1024]
  unsigned short* Vt   = (unsigned short*)(ws + ((size_t)30 << 20));   //  8 MB [1024,4096]
  unsigned short* S    = (unsigned short*)(ws + ((size_t)38 << 20));   // 32 MB [4096,4096]

  const float qscale = 0.03125f;  // 1/sqrt(1024) folded into Wq
  cvt_kernel<<<4096, 256, 0, stream>>>(x, xb, SEQQ * DDIM, 1.0f);
  cvt_kernel<<<1024, 256, 0, stream>>>(Wq, Wcat, DDIM * DDIM, qscale);
  cvt_kernel<<<1024, 256, 0, stream>>>(Wk, Wcat + (1u << 20), DDIM * DDIM, 1.0f);
  cvt_kernel<<<1024, 256, 0, stream>>>(Wv, Wcat + (2u << 20), DDIM * DDIM, 1.0f);

  gemm_qkv<<<dim3(24, 32), 256, 0, stream>>>(xb, Wcat, Qb, Kb, Vt);
  gemm_qkt<<<dim3(32, 32), 256, 0, stream>>>(Qb, Kb, S);
  softmax_causal<<<SEQQ, 256, 0, stream>>>(S);
  gemm_pv<<<dim3(8, 32), 256, 0, stream>>>(S, Vt, out);
}

// Round 2
// 166.030 us; speedup vs baseline: 1.2401x; 1.2401x over previous
//
#include <hip/hip_runtime.h>
#include <hip/hip_bf16.h>
#include <cstdint>
#include <cstddef>

// SelfAttentionV2: x[4096,1024] fp32; Wq/Wk/Wv [1024,1024] fp32.
// out = softmax(causal((x Wq^T)(x Wk^T)^T / 32)) @ (x Wv^T), fp32 out.
//
// Pipeline (all bf16 MFMA):
//   cvt: x->xb bf16, W->Wcat bf16 (Wq scaled by 1/32)
//   gemm_qkv: C[4096,3072] = xb @ Wcat^T -> Qb,Kb row-major bf16; V stored transposed (Vt[1024][4096])
//   gemm_qkt: S = Qb @ Kb^T, lower-triangle tiles only, diag masked with -inf, bf16
//   softmax:  row softmax over causal prefix, in place, bf16 P
//   gemm_pv_split: out = P @ Vt^T, split-K (nc=(bi>>3)+1 chunks): chunk0 -> out direct,
//                  chunks>=1 -> fp32 partial tiles in dead ws region
//   reduce_pv: out[rows>=1024] += sum of partial tiles

#define SEQQ 4096
#define DDIM 1024

typedef __bf16 bf16x8 __attribute__((ext_vector_type(8)));
typedef float f32x4 __attribute__((ext_vector_type(4)));

__device__ __forceinline__ unsigned short f2bf(float f) {
  unsigned int u = __builtin_bit_cast(unsigned int, f);
  unsigned int r = u + 0x7FFFu + ((u >> 16) & 1u);  // RNE; -inf stays -inf
  return (unsigned short)(r >> 16);
}

__device__ __forceinline__ void gload_lds16(const void* g, void* lds) {
  __builtin_amdgcn_global_load_lds(
      (__attribute__((address_space(1))) void*)(uintptr_t)g,
      (__attribute__((address_space(3))) void*)(uintptr_t)lds, 16, 0, 0);
}

// ---- fp32 -> bf16 conversion with optional scale ----
__global__ __launch_bounds__(256) void cvt_kernel(const float* __restrict__ src,
                                                  unsigned short* __restrict__ dst,
                                                  int n, float scale) {
  int i = (blockIdx.x * 256 + threadIdx.x) * 4;
  if (i >= n) return;
  const float4 v = *reinterpret_cast<const float4*>(src + i);
  ushort4 o;
  o.x = f2bf(v.x * scale);
  o.y = f2bf(v.y * scale);
  o.z = f2bf(v.z * scale);
  o.w = f2bf(v.w * scale);
  *reinterpret_cast<ushort4*>(dst + i) = o;
}

// ---- shared GEMM building blocks (128x128 tile, BK=32, 4 waves) ----
// LDS tile: 128 rows x 32 bf16 (64B/row), st_16x32 XOR swizzle:
//   byte ^= ((row>>3)&1)<<5, applied to source on stage and to addr on read.

__device__ __forceinline__ void stage128x32(const unsigned short* gtile, size_t ld /*elems*/,
                                            unsigned short* lds, int wave, int lane) {
#pragma unroll
  for (int i = 0; i < 2; ++i) {
    const int c = wave * 2 + i;                 // chunk 0..7, 16 rows each
    const int row = c * 16 + (lane >> 2);
    const int kb = ((lane & 3) * 16) ^ (((row >> 3) & 1) << 5);  // inverse-swizzled source
    const char* src = (const char*)gtile + (size_t)row * (ld * 2) + kb;
    char* dst = (char*)lds + c * 1024;          // wave-uniform base; HW adds lane*16
    gload_lds16(src, dst);
  }
}

__device__ __forceinline__ void load_frags(const unsigned short* lds, int wrow, int lane,
                                           bf16x8 f[4]) {
  const int r0 = wrow + (lane & 15);
  const int kb = (lane >> 4) * 16;
#pragma unroll
  for (int m = 0; m < 4; ++m) {
    int off = ((r0 + m * 16) << 6) + kb;        // row*64 + kbyte
    off ^= ((off >> 9) & 1) << 5;               // swizzled read
    f[m] = *reinterpret_cast<const bf16x8*>((const char*)lds + off);
  }
}

#define GEMM_PREAMBLE()                                        \
  __shared__ unsigned short As[128 * 32] __attribute__((aligned(16))); \
  __shared__ unsigned short Bs[128 * 32] __attribute__((aligned(16))); \
  const int tid = threadIdx.x;                                 \
  const int wave = tid >> 6, lane = tid & 63;                  \
  const int wr = (wave >> 1) * 64, wc = (wave & 1) * 64;       \
  f32x4 acc[4][4] = {};

#define GEMM_KSTEP(Aptr, lda, Bptr, ldb)                       \
  do {                                                         \
    stage128x32((Aptr), (lda), As, wave, lane);                \
    stage128x32((Bptr), (ldb), Bs, wave, lane);                \
    __syncthreads();                                           \
    bf16x8 a[4], b[4];                                         \
    load_frags(As, wr, lane, a);                               \
    load_frags(Bs, wc, lane, b);                               \
    _Pragma("unroll")                                          \
    for (int m = 0; m < 4; ++m)                                \
      _Pragma("unroll")                                        \
      for (int n = 0; n < 4; ++n)                              \
        acc[m][n] = __builtin_amdgcn_mfma_f32_16x16x32_bf16(   \
            a[m], b[n], acc[m][n], 0, 0, 0);                   \
    __syncthreads();                                           \
  } while (0)

// ---- QKV: C[4096,3072] = xb @ Wcat^T; Q,K row-major; V transposed ----
__global__ __launch_bounds__(256) void gemm_qkv(const unsigned short* __restrict__ X,
                                                const unsigned short* __restrict__ W,
                                                unsigned short* __restrict__ Qb,
                                                unsigned short* __restrict__ Kb,
                                                unsigned short* __restrict__ Vt) {
  GEMM_PREAMBLE();
  const int brow = blockIdx.y * 128, bcol = blockIdx.x * 128;
  for (int k0 = 0; k0 < DDIM; k0 += 32) {
    GEMM_KSTEP(X + (size_t)brow * DDIM + k0, DDIM,
               W + (size_t)bcol * DDIM + k0, DDIM);
  }
  const int region = bcol >> 10;  // 0=Q 1=K 2=V
  const int lcol = bcol & 1023;
  const int c0 = wc + (lane & 15);
  const int r0 = wr + ((lane >> 4) << 2);
  if (region < 2) {
    unsigned short* dst = (region == 0) ? Qb : Kb;
#pragma unroll
    for (int m = 0; m < 4; ++m) {
      const int r = brow + r0 + m * 16;
#pragma unroll
      for (int n = 0; n < 4; ++n) {
        const int c = lcol + c0 + n * 16;
#pragma unroll
        for (int j = 0; j < 4; ++j)
          dst[(size_t)(r + j) * DDIM + c] = f2bf(acc[m][n][j]);
      }
    }
  } else {
#pragma unroll
    for (int m = 0; m < 4; ++m) {
      const int r = brow + r0 + m * 16;
#pragma unroll
      for (int n = 0; n < 4; ++n) {
        const int c = lcol + c0 + n * 16;
        ushort4 pk;
        pk.x = f2bf(acc[m][n][0]);
        pk.y = f2bf(acc[m][n][1]);
        pk.z = f2bf(acc[m][n][2]);
        pk.w = f2bf(acc[m][n][3]);
        *reinterpret_cast<ushort4*>(Vt + (size_t)c * SEQQ + r) = pk;
      }
    }
  }
}

// ---- QK^T: S = Qb @ Kb^T, lower-triangle tiles, causal mask on diag ----
__global__ __launch_bounds__(256) void gemm_qkt(const unsigned short* __restrict__ Qb,
                                                const unsigned short* __restrict__ Kb,
                                                unsigned short* __restrict__ S) {
  const int bi = blockIdx.y, bj = blockIdx.x;
  if (bj > bi) return;  // upper-triangle tiles never computed nor read
  GEMM_PREAMBLE();
  const int brow = bi * 128, bcol = bj * 128;
  for (int k0 = 0; k0 < DDIM; k0 += 32) {
    GEMM_KSTEP(Qb + (size_t)brow * DDIM + k0, DDIM,
               Kb + (size_t)bcol * DDIM + k0, DDIM);
  }
  const int c0 = wc + (lane & 15);
  const int r0 = wr + ((lane >> 4) << 2);
#pragma unroll
  for (int m = 0; m < 4; ++m) {
    const int r = brow + r0 + m * 16;
#pragma unroll
    for (int n = 0; n < 4; ++n) {
      const int c = bcol + c0 + n * 16;
#pragma unroll
      for (int j = 0; j < 4; ++j) {
        unsigned short o = (c > r + j) ? (unsigned short)0xFF80  // -inf bf16
                                       : f2bf(acc[m][n][j]);
        S[(size_t)(r + j) * SEQQ + c] = o;
      }
    }
  }
}

// ---- row softmax over causal prefix, in place ----
__global__ __launch_bounds__(256) void softmax_causal(unsigned short* __restrict__ S) {
  const int row = blockIdx.x;
  const int L = ((row >> 7) + 1) << 7;  // multiple of 128 covering row+1
  unsigned short* Srow = S + (size_t)row * SEQQ;
  __shared__ float red[4];
  const int tid = threadIdx.x;
  const int lane = tid & 63, wave = tid >> 6;

  float x[16];
  bool have[2];
  float m = -3.0e38f;
#pragma unroll
  for (int it = 0; it < 2; ++it) {
    const int j = tid * 8 + it * 2048;
    have[it] = (j < L);
    if (have[it]) {
      const uint4 v = *reinterpret_cast<const uint4*>(Srow + j);
      const unsigned u[4] = {v.x, v.y, v.z, v.w};
#pragma unroll
      for (int q = 0; q < 4; ++q) {
        x[it * 8 + q * 2] = __builtin_bit_cast(float, u[q] << 16);
        x[it * 8 + q * 2 + 1] = __builtin_bit_cast(float, u[q] & 0xFFFF0000u);
      }
#pragma unroll
      for (int q = 0; q < 8; ++q) m = fmaxf(m, x[it * 8 + q]);
    }
  }
#pragma unroll
  for (int o = 32; o; o >>= 1) m = fmaxf(m, __shfl_xor(m, o));
  if (lane == 0) red[wave] = m;
  __syncthreads();
  m = fmaxf(fmaxf(red[0], red[1]), fmaxf(red[2], red[3]));
  __syncthreads();

  float sum = 0.f;
#pragma unroll
  for (int it = 0; it < 2; ++it)
    if (have[it]) {
#pragma unroll
      for (int q = 0; q < 8; ++q) {
        x[it * 8 + q] = __expf(x[it * 8 + q] - m);  // exp(-inf)=0 for masked
        sum += x[it * 8 + q];
      }
    }
#pragma unroll
  for (int o = 32; o; o >>= 1) sum += __shfl_xor(sum, o);
  if (lane == 0) red[wave] = sum;
  __syncthreads();
  sum = red[0] + red[1] + red[2] + red[3];
  const float inv = 1.0f / sum;

#pragma unroll
  for (int it = 0; it < 2; ++it)
    if (have[it]) {
      const int j = tid * 8 + it * 2048;
      unsigned u[4];
#pragma unroll
      for (int q = 0; q < 4; ++q) {
        u[q] = (unsigned)f2bf(x[it * 8 + q * 2] * inv) |
               ((unsigned)f2bf(x[it * 8 + q * 2 + 1] * inv) << 16);
      }
      *reinterpret_cast<uint4*>(Srow + j) = make_uint4(u[0], u[1], u[2], u[3]);
    }
}

// ---- partial-tile index helpers for split-K PV ----
// nc(bi) = (bi>>3)+1 chunks. Chunk 0 -> direct to out; chunks c>=1 -> partial
// tile rc = rcBase(bi) + (c-1), 8 bj tiles per rc, 64KB fp32 each.
__device__ __forceinline__ int pv_nc(int bi) { return (bi >> 3) + 1; }
__device__ __forceinline__ int pv_rcbase(int bi) {
  const int g = bi >> 3;  // 1..3 for bi>=8
  return (g == 1) ? (bi - 8) : (g == 2) ? 8 + (bi - 16) * 2 : 24 + (bi - 24) * 3;
}

// ---- PV split-K: out/partials = P @ Vt^T ----
__global__ __launch_bounds__(256) void gemm_pv_split(const unsigned short* __restrict__ P,
                                                     const unsigned short* __restrict__ Vt,
                                                     float* __restrict__ O,
                                                     float* __restrict__ part) {
  const int bj = blockIdx.x, bi = blockIdx.y, ck = blockIdx.z;
  const int nc = pv_nc(bi);
  if (ck >= nc) return;
  const int steps = (bi + 1) * 4;               // K-steps of 32 elems
  const int W = (steps + nc - 1) / nc;
  const int s0 = ck * W;
  const int s1 = min(s0 + W, steps);
  if (s0 >= s1) return;

  GEMM_PREAMBLE();
  const int brow = bi * 128, bcol = bj * 128;
  for (int ks = s0; ks < s1; ++ks) {
    const int k0 = ks * 32;
    GEMM_KSTEP(P + (size_t)brow * SEQQ + k0, SEQQ,
               Vt + (size_t)bcol * SEQQ + k0, SEQQ);
  }
  const int c0 = wc + (lane & 15);
  const int r0 = wr + ((lane >> 4) << 2);
  if (ck == 0) {
#pragma unroll
    for (int m = 0; m < 4; ++m) {
      const int r = brow + r0 + m * 16;
#pragma unroll
      for (int n = 0; n < 4; ++n) {
        const int c = bcol + c0 + n * 16;
#pragma unroll
        for (int j = 0; j < 4; ++j)
          O[(size_t)(r + j) * DDIM + c] = acc[m][n][j];
      }
    }
  } else {
    float* tile = part + ((size_t)(pv_rcbase(bi) + (ck - 1)) * 8 + bj) * 16384;
#pragma unroll
    for (int m = 0; m < 4; ++m) {
      const int lr = r0 + m * 16;
#pragma unroll
      for (int n = 0; n < 4; ++n) {
        const int lc = c0 + n * 16;
#pragma unroll
        for (int j = 0; j < 4; ++j)
          tile[(lr + j) * 128 + lc] = acc[m][n][j];
      }
    }
  }
}

// ---- add partial tiles into out rows >= 1024 ----
__global__ __launch_bounds__(256) void reduce_pv(float* __restrict__ O,
                                                 const float* __restrict__ part) {
  const int idx = blockIdx.x * 256 + threadIdx.x;   // one float4 per thread
  const int r = 1024 + (idx >> 8);                  // 256 float4s per row
  const int cc = (idx & 255) * 4;
  const int bi = r >> 7;
  const int nparts = pv_nc(bi) - 1;
  const int rcb = pv_rcbase(bi);
  const int bj = cc >> 7;
  const int lr = r & 127, lc = cc & 127;
  float4 acc = *reinterpret_cast<float4*>(O + (size_t)r * DDIM + cc);
  for (int k = 0; k < nparts; ++k) {
    const float4 p = *reinterpret_cast<const float4*>(
        part + ((size_t)(rcb + k) * 8 + bj) * 16384 + lr * 128 + lc);
    acc.x += p.x; acc.y += p.y; acc.z += p.z; acc.w += p.w;
  }
  *reinterpret_cast<float4*>(O + (size_t)r * DDIM + cc) = acc;
}

extern "C" void kernel_launch(void* const* d_in, const int* in_sizes, int n_in,
                              void* d_out, int out_size, void* d_ws, size_t ws_size,
                              hipStream_t stream) {
  (void)in_sizes; (void)n_in; (void)out_size; (void)ws_size;
  const float* x = (const float*)d_in[0];
  const float* Wq = (const float*)d_in[1];
  const float* Wk = (const float*)d_in[2];
  const float* Wv = (const float*)d_in[3];
  float* out = (float*)d_out;

  char* ws = (char*)d_ws;
  unsigned short* xb   = (unsigned short*)(ws);                        //  8 MB [4096,1024]
  unsigned short* Wcat = (unsigned short*)(ws + ((size_t)8 << 20));    //  6 MB [3072,1024]
  unsigned short* Qb   = (unsigned short*)(ws + ((size_t)14 << 20));   //  8 MB [4096,1024]
  unsigned short* Kb   = (unsigned short*)(ws + ((size_t)22 << 20));   //  8 MB [4096,1024]
  unsigned short* Vt   = (unsigned short*)(ws + ((size_t)30 << 20));   //  8 MB [1024,4096]
  unsigned short* S    = (unsigned short*)(ws + ((size_t)38 << 20));   // 32 MB [4096,4096]
  float* part = (float*)ws;  // 24 MB of partial tiles; reuses dead xb/Wcat/Qb/Kb region

  const float qscale = 0.03125f;  // 1/sqrt(1024) folded into Wq
  cvt_kernel<<<4096, 256, 0, stream>>>(x, xb, SEQQ * DDIM, 1.0f);
  cvt_kernel<<<1024, 256, 0, stream>>>(Wq, Wcat, DDIM * DDIM, qscale);
  cvt_kernel<<<1024, 256, 0, stream>>>(Wk, Wcat + (1u << 20), DDIM * DDIM, 1.0f);
  cvt_kernel<<<1024, 256, 0, stream>>>(Wv, Wcat + (2u << 20), DDIM * DDIM, 1.0f);

  gemm_qkv<<<dim3(24, 32), 256, 0, stream>>>(xb, Wcat, Qb, Kb, Vt);
  gemm_qkt<<<dim3(32, 32), 256, 0, stream>>>(Qb, Kb, S);
  softmax_causal<<<SEQQ, 256, 0, stream>>>(S);
  gemm_pv_split<<<dim3(8, 32, 4), 256, 0, stream>>>(S, Vt, out, part);
  reduce_pv<<<3072, 256, 0, stream>>>(out, part);
}

// Round 3
// 162.931 us; speedup vs baseline: 1.2637x; 1.0190x over previous
//
#include <hip/hip_runtime.h>
#include <hip/hip_bf16.h>
#include <cstdint>
#include <cstddef>

// SelfAttentionV2: x[4096,1024] fp32; Wq/Wk/Wv [1024,1024] fp32.
// out = softmax(causal((x Wq^T)(x Wk^T)^T / 32)) @ (x Wv^T), fp32 out.
//
// Pipeline (all bf16 MFMA):
//   cvt_all:  x->xb bf16, W->Wcat bf16 (Wq scaled by 1/32), one fused launch
//   gemm_qkv: C[4096,3072] = xb @ Wcat^T -> Qb,Kb row-major bf16; V transposed (Vt[1024][4096])
//   gemm_qkt: S = Qb @ Kb^T, lower-triangle tiles only, diag masked with -inf, bf16
//   softmax:  row softmax over causal prefix, in place, bf16 P
//   gemm_pv_split: out = P @ Vt^T, split-K; chunk0 -> out, chunks>=1 -> fp32 partials
//   reduce_pv: out[rows>=1024] += partials
//
// GEMM main loop: T3-minimum 2-phase — double-buffered LDS, next-tile
// global_load_lds issued BEFORE current tile's ds_read+MFMA, raw s_barrier
// with explicit vmcnt(0) drain per K-step (avoids compiler's conservative
// drain placement around __syncthreads).

#define SEQQ 4096
#define DDIM 1024

typedef __bf16 bf16x8 __attribute__((ext_vector_type(8)));
typedef float f32x4 __attribute__((ext_vector_type(4)));

__device__ __forceinline__ unsigned short f2bf(float f) {
  unsigned int u = __builtin_bit_cast(unsigned int, f);
  unsigned int r = u + 0x7FFFu + ((u >> 16) & 1u);  // RNE; -inf stays -inf
  return (unsigned short)(r >> 16);
}

__device__ __forceinline__ void gload_lds16(const void* g, void* lds) {
  __builtin_amdgcn_global_load_lds(
      (__attribute__((address_space(1))) void*)(uintptr_t)g,
      (__attribute__((address_space(3))) void*)(uintptr_t)lds, 16, 0, 0);
}

// ---- fused fp32 -> bf16 conversion (x, Wq*1/32, Wk, Wv) ----
__global__ __launch_bounds__(256) void cvt_all(const float* __restrict__ x,
                                               const float* __restrict__ Wq,
                                               const float* __restrict__ Wk,
                                               const float* __restrict__ Wv,
                                               unsigned short* __restrict__ xb,
                                               unsigned short* __restrict__ Wcat) {
  int b = blockIdx.x;
  const float* src;
  unsigned short* dst;
  float scale = 1.0f;
  if (b < 4096) {
    src = x; dst = xb;
  } else if (b < 5120) {
    src = Wq; dst = Wcat; scale = 0.03125f; b -= 4096;
  } else if (b < 6144) {
    src = Wk; dst = Wcat + (1u << 20); b -= 5120;
  } else {
    src = Wv; dst = Wcat + (2u << 20); b -= 6144;
  }
  const int i = (b * 256 + threadIdx.x) * 4;
  const float4 v = *reinterpret_cast<const float4*>(src + i);
  ushort4 o;
  o.x = f2bf(v.x * scale);
  o.y = f2bf(v.y * scale);
  o.z = f2bf(v.z * scale);
  o.w = f2bf(v.w * scale);
  *reinterpret_cast<ushort4*>(dst + i) = o;
}

// ---- shared GEMM building blocks (128x128 tile, BK=32, 4 waves) ----
// LDS tile: 128 rows x 32 bf16 (64B/row), st_16x32 XOR swizzle:
//   byte ^= ((row>>3)&1)<<5, applied to source on stage and to addr on read.

__device__ __forceinline__ void stage128x32(const unsigned short* gtile, size_t ld /*elems*/,
                                            unsigned short* lds, int wave, int lane) {
#pragma unroll
  for (int i = 0; i < 2; ++i) {
    const int c = wave * 2 + i;                 // chunk 0..7, 16 rows each
    const int row = c * 16 + (lane >> 2);
    const int kb = ((lane & 3) * 16) ^ (((row >> 3) & 1) << 5);  // inverse-swizzled source
    const char* src = (const char*)gtile + (size_t)row * (ld * 2) + kb;
    char* dst = (char*)lds + c * 1024;          // wave-uniform base; HW adds lane*16
    gload_lds16(src, dst);
  }
}

__device__ __forceinline__ void load_frags(const unsigned short* lds, int wrow, int lane,
                                           bf16x8 f[4]) {
  const int r0 = wrow + (lane & 15);
  const int kb = (lane >> 4) * 16;
#pragma unroll
  for (int m = 0; m < 4; ++m) {
    int off = ((r0 + m * 16) << 6) + kb;        // row*64 + kbyte
    off ^= ((off >> 9) & 1) << 5;               // swizzled read
    f[m] = *reinterpret_cast<const bf16x8*>((const char*)lds + off);
  }
}

#define GEMM_PREAMBLE()                                                     \
  __shared__ unsigned short As[2][4096] __attribute__((aligned(16)));       \
  __shared__ unsigned short Bs[2][4096] __attribute__((aligned(16)));       \
  const int tid = threadIdx.x;                                              \
  const int wave = tid >> 6, lane = tid & 63;                               \
  const int wr = (wave >> 1) * 64, wc = (wave & 1) * 64;                    \
  f32x4 acc[4][4] = {};

// 2-phase double-buffered K loop over steps [S0,S1); ABASE/BBASE are element
// pointers to the tile's row 0 at k=0; step s reads k-slab [s*32, s*32+32).
#define GEMM_LOOP(ABASE, LDA, BBASE, LDB, S0, S1)                           \
  do {                                                                      \
    int cur = 0;                                                            \
    stage128x32((ABASE) + (size_t)(S0) * 32, (LDA), As[0], wave, lane);     \
    stage128x32((BBASE) + (size_t)(S0) * 32, (LDB), Bs[0], wave, lane);     \
    asm volatile("s_waitcnt vmcnt(0) lgkmcnt(0)" ::: "memory");             \
    __builtin_amdgcn_s_barrier();                                           \
    for (int s = (S0); s < (S1); ++s) {                                     \
      if (s + 1 < (S1)) {                                                   \
        stage128x32((ABASE) + (size_t)(s + 1) * 32, (LDA), As[cur ^ 1],     \
                    wave, lane);                                            \
        stage128x32((BBASE) + (size_t)(s + 1) * 32, (LDB), Bs[cur ^ 1],     \
                    wave, lane);                                            \
      }                                                                     \
      bf16x8 a[4], b[4];                                                    \
      load_frags(As[cur], wr, lane, a);                                     \
      load_frags(Bs[cur], wc, lane, b);                                     \
      _Pragma("unroll")                                                     \
      for (int m = 0; m < 4; ++m)                                           \
        _Pragma("unroll")                                                   \
        for (int n = 0; n < 4; ++n)                                         \
          acc[m][n] = __builtin_amdgcn_mfma_f32_16x16x32_bf16(              \
              a[m], b[n], acc[m][n], 0, 0, 0);                              \
      asm volatile("s_waitcnt vmcnt(0) lgkmcnt(0)" ::: "memory");           \
      __builtin_amdgcn_s_barrier();                                         \
      cur ^= 1;                                                             \
    }                                                                       \
  } while (0)

// ---- QKV: C[4096,3072] = xb @ Wcat^T; Q,K row-major; V transposed ----
__global__ __launch_bounds__(256) void gemm_qkv(const unsigned short* __restrict__ X,
                                                const unsigned short* __restrict__ W,
                                                unsigned short* __restrict__ Qb,
                                                unsigned short* __restrict__ Kb,
                                                unsigned short* __restrict__ Vt) {
  GEMM_PREAMBLE();
  const int brow = blockIdx.y * 128, bcol = blockIdx.x * 128;
  GEMM_LOOP(X + (size_t)brow * DDIM, DDIM, W + (size_t)bcol * DDIM, DDIM, 0, 32);
  const int region = bcol >> 10;  // 0=Q 1=K 2=V
  const int lcol = bcol & 1023;
  const int c0 = wc + (lane & 15);
  const int r0 = wr + ((lane >> 4) << 2);
  if (region < 2) {
    unsigned short* dst = (region == 0) ? Qb : Kb;
#pragma unroll
    for (int m = 0; m < 4; ++m) {
      const int r = brow + r0 + m * 16;
#pragma unroll
      for (int n = 0; n < 4; ++n) {
        const int c = lcol + c0 + n * 16;
#pragma unroll
        for (int j = 0; j < 4; ++j)
          dst[(size_t)(r + j) * DDIM + c] = f2bf(acc[m][n][j]);
      }
    }
  } else {
#pragma unroll
    for (int m = 0; m < 4; ++m) {
      const int r = brow + r0 + m * 16;
#pragma unroll
      for (int n = 0; n < 4; ++n) {
        const int c = lcol + c0 + n * 16;
        ushort4 pk;
        pk.x = f2bf(acc[m][n][0]);
        pk.y = f2bf(acc[m][n][1]);
        pk.z = f2bf(acc[m][n][2]);
        pk.w = f2bf(acc[m][n][3]);
        *reinterpret_cast<ushort4*>(Vt + (size_t)c * SEQQ + r) = pk;
      }
    }
  }
}

// ---- QK^T: S = Qb @ Kb^T, lower-triangle tiles, causal mask on diag ----
__global__ __launch_bounds__(256) void gemm_qkt(const unsigned short* __restrict__ Qb,
                                                const unsigned short* __restrict__ Kb,
                                                unsigned short* __restrict__ S) {
  const int bi = blockIdx.y, bj = blockIdx.x;
  if (bj > bi) return;  // upper-triangle tiles never computed nor read
  GEMM_PREAMBLE();
  const int brow = bi * 128, bcol = bj * 128;
  GEMM_LOOP(Qb + (size_t)brow * DDIM, DDIM, Kb + (size_t)bcol * DDIM, DDIM, 0, 32);
  const int c0 = wc + (lane & 15);
  const int r0 = wr + ((lane >> 4) << 2);
#pragma unroll
  for (int m = 0; m < 4; ++m) {
    const int r = brow + r0 + m * 16;
#pragma unroll
    for (int n = 0; n < 4; ++n) {
      const int c = bcol + c0 + n * 16;
#pragma unroll
      for (int j = 0; j < 4; ++j) {
        unsigned short o = (c > r + j) ? (unsigned short)0xFF80  // -inf bf16
                                       : f2bf(acc[m][n][j]);
        S[(size_t)(r + j) * SEQQ + c] = o;
      }
    }
  }
}

// ---- row softmax over causal prefix, in place ----
__global__ __launch_bounds__(256) void softmax_causal(unsigned short* __restrict__ S) {
  const int row = blockIdx.x;
  const int L = ((row >> 7) + 1) << 7;  // multiple of 128 covering row+1
  unsigned short* Srow = S + (size_t)row * SEQQ;
  __shared__ float red[4];
  const int tid = threadIdx.x;
  const int lane = tid & 63, wave = tid >> 6;

  float x[16];
  bool have[2];
  float m = -3.0e38f;
#pragma unroll
  for (int it = 0; it < 2; ++it) {
    const int j = tid * 8 + it * 2048;
    have[it] = (j < L);
    if (have[it]) {
      const uint4 v = *reinterpret_cast<const uint4*>(Srow + j);
      const unsigned u[4] = {v.x, v.y, v.z, v.w};
#pragma unroll
      for (int q = 0; q < 4; ++q) {
        x[it * 8 + q * 2] = __builtin_bit_cast(float, u[q] << 16);
        x[it * 8 + q * 2 + 1] = __builtin_bit_cast(float, u[q] & 0xFFFF0000u);
      }
#pragma unroll
      for (int q = 0; q < 8; ++q) m = fmaxf(m, x[it * 8 + q]);
    }
  }
#pragma unroll
  for (int o = 32; o; o >>= 1) m = fmaxf(m, __shfl_xor(m, o));
  if (lane == 0) red[wave] = m;
  __syncthreads();
  m = fmaxf(fmaxf(red[0], red[1]), fmaxf(red[2], red[3]));
  __syncthreads();

  float sum = 0.f;
#pragma unroll
  for (int it = 0; it < 2; ++it)
    if (have[it]) {
#pragma unroll
      for (int q = 0; q < 8; ++q) {
        x[it * 8 + q] = __expf(x[it * 8 + q] - m);  // exp(-inf)=0 for masked
        sum += x[it * 8 + q];
      }
    }
#pragma unroll
  for (int o = 32; o; o >>= 1) sum += __shfl_xor(sum, o);
  if (lane == 0) red[wave] = sum;
  __syncthreads();
  sum = red[0] + red[1] + red[2] + red[3];
  const float inv = 1.0f / sum;

#pragma unroll
  for (int it = 0; it < 2; ++it)
    if (have[it]) {
      const int j = tid * 8 + it * 2048;
      unsigned u[4];
#pragma unroll
      for (int q = 0; q < 4; ++q) {
        u[q] = (unsigned)f2bf(x[it * 8 + q * 2] * inv) |
               ((unsigned)f2bf(x[it * 8 + q * 2 + 1] * inv) << 16);
      }
      *reinterpret_cast<uint4*>(Srow + j) = make_uint4(u[0], u[1], u[2], u[3]);
    }
}

// ---- partial-tile index helpers for split-K PV ----
// nc(bi) = (bi>>3)+1 chunks. Chunk 0 -> direct to out; chunks c>=1 -> partial
// tile rc = rcBase(bi) + (c-1), 8 bj tiles per rc, 64KB fp32 each.
__device__ __forceinline__ int pv_nc(int bi) { return (bi >> 3) + 1; }
__device__ __forceinline__ int pv_rcbase(int bi) {
  const int g = bi >> 3;  // 1..3 for bi>=8
  return (g == 1) ? (bi - 8) : (g == 2) ? 8 + (bi - 16) * 2 : 24 + (bi - 24) * 3;
}

// ---- PV split-K: out/partials = P @ Vt^T ----
__global__ __launch_bounds__(256) void gemm_pv_split(const unsigned short* __restrict__ P,
                                                     const unsigned short* __restrict__ Vt,
                                                     float* __restrict__ O,
                                                     float* __restrict__ part) {
  const int bj = blockIdx.x, bi = blockIdx.y, ck = blockIdx.z;
  const int nc = pv_nc(bi);
  if (ck >= nc) return;
  const int steps = (bi + 1) * 4;               // K-steps of 32 elems
  const int W = (steps + nc - 1) / nc;
  const int s0 = ck * W;
  const int s1 = min(s0 + W, steps);
  if (s0 >= s1) return;

  GEMM_PREAMBLE();
  const int brow = bi * 128, bcol = bj * 128;
  GEMM_LOOP(P + (size_t)brow * SEQQ, SEQQ, Vt + (size_t)bcol * SEQQ, SEQQ, s0, s1);
  const int c0 = wc + (lane & 15);
  const int r0 = wr + ((lane >> 4) << 2);
  if (ck == 0) {
#pragma unroll
    for (int m = 0; m < 4; ++m) {
      const int r = brow + r0 + m * 16;
#pragma unroll
      for (int n = 0; n < 4; ++n) {
        const int c = bcol + c0 + n * 16;
#pragma unroll
        for (int j = 0; j < 4; ++j)
          O[(size_t)(r + j) * DDIM + c] = acc[m][n][j];
      }
    }
  } else {
    float* tile = part + ((size_t)(pv_rcbase(bi) + (ck - 1)) * 8 + bj) * 16384;
#pragma unroll
    for (int m = 0; m < 4; ++m) {
      const int lr = r0 + m * 16;
#pragma unroll
      for (int n = 0; n < 4; ++n) {
        const int lc = c0 + n * 16;
#pragma unroll
        for (int j = 0; j < 4; ++j)
          tile[(lr + j) * 128 + lc] = acc[m][n][j];
      }
    }
  }
}

// ---- add partial tiles into out rows >= 1024 ----
__global__ __launch_bounds__(256) void reduce_pv(float* __restrict__ O,
                                                 const float* __restrict__ part) {
  const int idx = blockIdx.x * 256 + threadIdx.x;   // one float4 per thread
  const int r = 1024 + (idx >> 8);                  // 256 float4s per row
  const int cc = (idx & 255) * 4;
  const int bi = r >> 7;
  const int nparts = pv_nc(bi) - 1;
  const int rcb = pv_rcbase(bi);
  const int bj = cc >> 7;
  const int lr = r & 127, lc = cc & 127;
  float4 acc = *reinterpret_cast<float4*>(O + (size_t)r * DDIM + cc);
  for (int k = 0; k < nparts; ++k) {
    const float4 p = *reinterpret_cast<const float4*>(
        part + ((size_t)(rcb + k) * 8 + bj) * 16384 + lr * 128 + lc);
    acc.x += p.x; acc.y += p.y; acc.z += p.z; acc.w += p.w;
  }
  *reinterpret_cast<float4*>(O + (size_t)r * DDIM + cc) = acc;
}

extern "C" void kernel_launch(void* const* d_in, const int* in_sizes, int n_in,
                              void* d_out, int out_size, void* d_ws, size_t ws_size,
                              hipStream_t stream) {
  (void)in_sizes; (void)n_in; (void)out_size; (void)ws_size;
  const float* x = (const float*)d_in[0];
  const float* Wq = (const float*)d_in[1];
  const float* Wk = (const float*)d_in[2];
  const float* Wv = (const float*)d_in[3];
  float* out = (float*)d_out;

  char* ws = (char*)d_ws;
  unsigned short* xb   = (unsigned short*)(ws);                        //  8 MB [4096,1024]
  unsigned short* Wcat = (unsigned short*)(ws + ((size_t)8 << 20));    //  6 MB [3072,1024]
  unsigned short* Qb   = (unsigned short*)(ws + ((size_t)14 << 20));   //  8 MB [4096,1024]
  unsigned short* Kb   = (unsigned short*)(ws + ((size_t)22 << 20));   //  8 MB [4096,1024]
  unsigned short* Vt   = (unsigned short*)(ws + ((size_t)30 << 20));   //  8 MB [1024,4096]
  unsigned short* S    = (unsigned short*)(ws + ((size_t)38 << 20));   // 32 MB [4096,4096]
  float* part = (float*)ws;  // 24 MB of partial tiles; reuses dead xb/Wcat/Qb/Kb region

  cvt_all<<<7168, 256, 0, stream>>>(x, Wq, Wk, Wv, xb, Wcat);
  gemm_qkv<<<dim3(24, 32), 256, 0, stream>>>(xb, Wcat, Qb, Kb, Vt);
  gemm_qkt<<<dim3(32, 32), 256, 0, stream>>>(Qb, Kb, S);
  softmax_causal<<<SEQQ, 256, 0, stream>>>(S);
  gemm_pv_split<<<dim3(8, 32, 4), 256, 0, stream>>>(S, Vt, out, part);
  reduce_pv<<<3072, 256, 0, stream>>>(out, part);
}

// Round 4
// 151.858 us; speedup vs baseline: 1.3559x; 1.0729x over previous
//
#include <hip/hip_runtime.h>
#include <hip/hip_bf16.h>
#include <cstdint>
#include <cstddef>

// SelfAttentionV2: x[4096,1024] fp32; Wq/Wk/Wv [1024,1024] fp32.
// out = softmax(causal((x Wq^T)(x Wk^T)^T / 32)) @ (x Wv^T), fp32 out.
//
// Pipeline (all bf16 MFMA):
//   cvt_all:  x->xb bf16, W->Wcat bf16 (Wq scaled by 1/32), one fused launch
//   gemm_qkv: C[4096,3072] = xb @ Wcat^T -> Qb,Kb row-major bf16; V transposed (Vt[1024][4096])
//   gemm_qkt: S = Qb @ Kb^T, lower-triangle tiles only, diag masked with -inf, bf16
//   softmax:  row softmax over causal prefix, in place, bf16 P
//   gemm_pv_split: out = P @ Vt^T, split-K; chunk0 -> out, chunks>=1 -> fp32 partials
//   reduce_pv: out[rows>=1024] += partials
//
// GEMM main loop: 128x128 tile, BK=64, single-buffer (32KB LDS -> 3 blocks/CU),
// 16 K-steps instead of 32 (halves barrier/drain events per block — the measured
// bottleneck). All staging/frag addresses hoisted out of the K-loop.
// LDS rows are 128B => XOR swizzle byte ^= ((row&7)<<4), applied to the
// global SOURCE on stage (global_load_lds writes linearly) and to the
// ds_read address (same involution both sides).

#define SEQQ 4096
#define DDIM 1024

typedef __bf16 bf16x8 __attribute__((ext_vector_type(8)));
typedef float f32x4 __attribute__((ext_vector_type(4)));

__device__ __forceinline__ unsigned short f2bf(float f) {
  unsigned int u = __builtin_bit_cast(unsigned int, f);
  unsigned int r = u + 0x7FFFu + ((u >> 16) & 1u);  // RNE; -inf stays -inf
  return (unsigned short)(r >> 16);
}

__device__ __forceinline__ void gload_lds16(const void* g, void* lds) {
  __builtin_amdgcn_global_load_lds(
      (__attribute__((address_space(1))) void*)(uintptr_t)g,
      (__attribute__((address_space(3))) void*)(uintptr_t)lds, 16, 0, 0);
}

// ---- fused fp32 -> bf16 conversion (x, Wq*1/32, Wk, Wv) ----
__global__ __launch_bounds__(256) void cvt_all(const float* __restrict__ x,
                                               const float* __restrict__ Wq,
                                               const float* __restrict__ Wk,
                                               const float* __restrict__ Wv,
                                               unsigned short* __restrict__ xb,
                                               unsigned short* __restrict__ Wcat) {
  int b = blockIdx.x;
  const float* src;
  unsigned short* dst;
  float scale = 1.0f;
  if (b < 4096) {
    src = x; dst = xb;
  } else if (b < 5120) {
    src = Wq; dst = Wcat; scale = 0.03125f; b -= 4096;
  } else if (b < 6144) {
    src = Wk; dst = Wcat + (1u << 20); b -= 5120;
  } else {
    src = Wv; dst = Wcat + (2u << 20); b -= 6144;
  }
  const int i = (b * 256 + threadIdx.x) * 4;
  const float4 v = *reinterpret_cast<const float4*>(src + i);
  ushort4 o;
  o.x = f2bf(v.x * scale);
  o.y = f2bf(v.y * scale);
  o.z = f2bf(v.z * scale);
  o.w = f2bf(v.w * scale);
  *reinterpret_cast<ushort4*>(dst + i) = o;
}

// ---- GEMM building blocks: 128x128 tile, BK=64, 4 waves, single LDS buffer ----
// LDS tile [128][64] bf16 (128B rows). Stage: 16 chunks of 1KB (8 rows each);
// chunk c = i*4+wave, lane l writes row c*8 + l/8, colb (l&7)*16, with the
// source column pre-XORed by ((row&7)<<4) = ((l>>3)<<4).

__device__ __forceinline__ void stage_init(const unsigned short* gtile, size_t ld,
                                           const char* p[4], int wave, int lane) {
  const int lrow = lane >> 3;                                 // 0..7 = row&7
  const int colb = ((lane & 7) * 16) ^ (lrow << 4);           // inverse-swizzled source
#pragma unroll
  for (int i = 0; i < 4; ++i) {
    const int row = (i * 4 + wave) * 8 + lrow;
    p[i] = (const char*)gtile + (size_t)row * (ld * 2) + colb;
  }
}

__device__ __forceinline__ void stage_issue(const char* p[4], unsigned short* lds, int wave) {
#pragma unroll
  for (int i = 0; i < 4; ++i)
    gload_lds16(p[i], (char*)lds + (i * 4 + wave) * 1024);
}

// Precompute the 8 swizzled frag addresses per operand (m=0..3, kk=0..1).
__device__ __forceinline__ void frag_addrs(const unsigned short* lds, int wrow, int lane,
                                           const unsigned short* fa[4][2]) {
  const int rbase = wrow + (lane & 15);
  const int cb = (lane >> 4) * 16;
#pragma unroll
  for (int m = 0; m < 4; ++m) {
    const int r = rbase + m * 16;
    const int sw = (r & 7) << 4;
    fa[m][0] = (const unsigned short*)((const char*)lds + r * 128 + (cb ^ sw));
    fa[m][1] = (const unsigned short*)((const char*)lds + r * 128 + ((64 + cb) ^ sw));
  }
}

#define GEMM_PREAMBLE()                                                     \
  __shared__ unsigned short As[128 * 64] __attribute__((aligned(16)));      \
  __shared__ unsigned short Bs[128 * 64] __attribute__((aligned(16)));      \
  const int tid = threadIdx.x;                                              \
  const int wave = tid >> 6, lane = tid & 63;                               \
  const int wr = (wave >> 1) * 64, wc = (wave & 1) * 64;                    \
  f32x4 acc[4][4] = {};

// K loop over BK=64 steps [S0,S1); step s covers elems [s*64, s*64+64).
#define GEMM_LOOP(ABASE, LDA, BBASE, LDB, S0, S1)                           \
  do {                                                                      \
    const char* pa[4];                                                      \
    const char* pb[4];                                                      \
    stage_init((ABASE) + (size_t)(S0) * 64, (LDA), pa, wave, lane);         \
    stage_init((BBASE) + (size_t)(S0) * 64, (LDB), pb, wave, lane);         \
    const unsigned short* fa[4][2];                                         \
    const unsigned short* fb[4][2];                                         \
    frag_addrs(As, wr, lane, fa);                                           \
    frag_addrs(Bs, wc, lane, fb);                                           \
    for (int s = (S0); s < (S1); ++s) {                                     \
      stage_issue(pa, As, wave);                                            \
      stage_issue(pb, Bs, wave);                                            \
      _Pragma("unroll")                                                     \
      for (int i = 0; i < 4; ++i) { pa[i] += 128; pb[i] += 128; }           \
      asm volatile("s_waitcnt vmcnt(0)" ::: "memory");                      \
      asm volatile("s_barrier" ::: "memory");                               \
      bf16x8 a[4][2], b[4][2];                                              \
      _Pragma("unroll")                                                     \
      for (int m = 0; m < 4; ++m) {                                         \
        a[m][0] = *reinterpret_cast<const bf16x8*>(fa[m][0]);               \
        a[m][1] = *reinterpret_cast<const bf16x8*>(fa[m][1]);               \
        b[m][0] = *reinterpret_cast<const bf16x8*>(fb[m][0]);               \
        b[m][1] = *reinterpret_cast<const bf16x8*>(fb[m][1]);               \
      }                                                                     \
      _Pragma("unroll")                                                     \
      for (int kk = 0; kk < 2; ++kk)                                        \
        _Pragma("unroll")                                                   \
        for (int m = 0; m < 4; ++m)                                         \
          _Pragma("unroll")                                                 \
          for (int n = 0; n < 4; ++n)                                       \
            acc[m][n] = __builtin_amdgcn_mfma_f32_16x16x32_bf16(            \
                a[m][kk], b[n][kk], acc[m][n], 0, 0, 0);                    \
      asm volatile("s_waitcnt lgkmcnt(0)" ::: "memory");                    \
      asm volatile("s_barrier" ::: "memory");                               \
    }                                                                       \
  } while (0)

// ---- QKV: C[4096,3072] = xb @ Wcat^T; Q,K row-major; V transposed ----
__global__ __launch_bounds__(256) void gemm_qkv(const unsigned short* __restrict__ X,
                                                const unsigned short* __restrict__ W,
                                                unsigned short* __restrict__ Qb,
                                                unsigned short* __restrict__ Kb,
                                                unsigned short* __restrict__ Vt) {
  GEMM_PREAMBLE();
  const int brow = blockIdx.y * 128, bcol = blockIdx.x * 128;
  GEMM_LOOP(X + (size_t)brow * DDIM, DDIM, W + (size_t)bcol * DDIM, DDIM, 0, 16);
  const int region = bcol >> 10;  // 0=Q 1=K 2=V
  const int lcol = bcol & 1023;
  const int c0 = wc + (lane & 15);
  const int r0 = wr + ((lane >> 4) << 2);
  if (region < 2) {
    unsigned short* dst = (region == 0) ? Qb : Kb;
#pragma unroll
    for (int m = 0; m < 4; ++m) {
      const int r = brow + r0 + m * 16;
#pragma unroll
      for (int n = 0; n < 4; ++n) {
        const int c = lcol + c0 + n * 16;
#pragma unroll
        for (int j = 0; j < 4; ++j)
          dst[(size_t)(r + j) * DDIM + c] = f2bf(acc[m][n][j]);
      }
    }
  } else {
#pragma unroll
    for (int m = 0; m < 4; ++m) {
      const int r = brow + r0 + m * 16;
#pragma unroll
      for (int n = 0; n < 4; ++n) {
        const int c = lcol + c0 + n * 16;
        ushort4 pk;
        pk.x = f2bf(acc[m][n][0]);
        pk.y = f2bf(acc[m][n][1]);
        pk.z = f2bf(acc[m][n][2]);
        pk.w = f2bf(acc[m][n][3]);
        *reinterpret_cast<ushort4*>(Vt + (size_t)c * SEQQ + r) = pk;
      }
    }
  }
}

// ---- QK^T: S = Qb @ Kb^T, lower-triangle tiles, causal mask on diag ----
__global__ __launch_bounds__(256) void gemm_qkt(const unsigned short* __restrict__ Qb,
                                                const unsigned short* __restrict__ Kb,
                                                unsigned short* __restrict__ S) {
  const int bi = blockIdx.y, bj = blockIdx.x;
  if (bj > bi) return;  // upper-triangle tiles never computed nor read
  GEMM_PREAMBLE();
  const int brow = bi * 128, bcol = bj * 128;
  GEMM_LOOP(Qb + (size_t)brow * DDIM, DDIM, Kb + (size_t)bcol * DDIM, DDIM, 0, 16);
  const int c0 = wc + (lane & 15);
  const int r0 = wr + ((lane >> 4) << 2);
#pragma unroll
  for (int m = 0; m < 4; ++m) {
    const int r = brow + r0 + m * 16;
#pragma unroll
    for (int n = 0; n < 4; ++n) {
      const int c = bcol + c0 + n * 16;
#pragma unroll
      for (int j = 0; j < 4; ++j) {
        unsigned short o = (c > r + j) ? (unsigned short)0xFF80  // -inf bf16
                                       : f2bf(acc[m][n][j]);
        S[(size_t)(r + j) * SEQQ + c] = o;
      }
    }
  }
}

// ---- row softmax over causal prefix, in place ----
__global__ __launch_bounds__(256) void softmax_causal(unsigned short* __restrict__ S) {
  const int row = blockIdx.x;
  const int L = ((row >> 7) + 1) << 7;  // multiple of 128 covering row+1
  unsigned short* Srow = S + (size_t)row * SEQQ;
  __shared__ float red[4];
  const int tid = threadIdx.x;
  const int lane = tid & 63, wave = tid >> 6;

  float x[16];
  bool have[2];
  float m = -3.0e38f;
#pragma unroll
  for (int it = 0; it < 2; ++it) {
    const int j = tid * 8 + it * 2048;
    have[it] = (j < L);
    if (have[it]) {
      const uint4 v = *reinterpret_cast<const uint4*>(Srow + j);
      const unsigned u[4] = {v.x, v.y, v.z, v.w};
#pragma unroll
      for (int q = 0; q < 4; ++q) {
        x[it * 8 + q * 2] = __builtin_bit_cast(float, u[q] << 16);
        x[it * 8 + q * 2 + 1] = __builtin_bit_cast(float, u[q] & 0xFFFF0000u);
      }
#pragma unroll
      for (int q = 0; q < 8; ++q) m = fmaxf(m, x[it * 8 + q]);
    }
  }
#pragma unroll
  for (int o = 32; o; o >>= 1) m = fmaxf(m, __shfl_xor(m, o));
  if (lane == 0) red[wave] = m;
  __syncthreads();
  m = fmaxf(fmaxf(red[0], red[1]), fmaxf(red[2], red[3]));
  __syncthreads();

  float sum = 0.f;
#pragma unroll
  for (int it = 0; it < 2; ++it)
    if (have[it]) {
#pragma unroll
      for (int q = 0; q < 8; ++q) {
        x[it * 8 + q] = __expf(x[it * 8 + q] - m);  // exp(-inf)=0 for masked
        sum += x[it * 8 + q];
      }
    }
#pragma unroll
  for (int o = 32; o; o >>= 1) sum += __shfl_xor(sum, o);
  if (lane == 0) red[wave] = sum;
  __syncthreads();
  sum = red[0] + red[1] + red[2] + red[3];
  const float inv = 1.0f / sum;

#pragma unroll
  for (int it = 0; it < 2; ++it)
    if (have[it]) {
      const int j = tid * 8 + it * 2048;
      unsigned u[4];
#pragma unroll
      for (int q = 0; q < 4; ++q) {
        u[q] = (unsigned)f2bf(x[it * 8 + q * 2] * inv) |
               ((unsigned)f2bf(x[it * 8 + q * 2 + 1] * inv) << 16);
      }
      *reinterpret_cast<uint4*>(Srow + j) = make_uint4(u[0], u[1], u[2], u[3]);
    }
}

// ---- partial-tile index helpers for split-K PV ----
// nc(bi) = (bi>>3)+1 chunks. Chunk 0 -> direct to out; chunks c>=1 -> partial
// tile rc = rcBase(bi) + (c-1), 8 bj tiles per rc, 64KB fp32 each.
__device__ __forceinline__ int pv_nc(int bi) { return (bi >> 3) + 1; }
__device__ __forceinline__ int pv_rcbase(int bi) {
  const int g = bi >> 3;  // 1..3 for bi>=8
  return (g == 1) ? (bi - 8) : (g == 2) ? 8 + (bi - 16) * 2 : 24 + (bi - 24) * 3;
}

// ---- PV split-K: out/partials = P @ Vt^T ----
__global__ __launch_bounds__(256) void gemm_pv_split(const unsigned short* __restrict__ P,
                                                     const unsigned short* __restrict__ Vt,
                                                     float* __restrict__ O,
                                                     float* __restrict__ part) {
  const int bj = blockIdx.x, bi = blockIdx.y, ck = blockIdx.z;
  const int nc = pv_nc(bi);
  if (ck >= nc) return;
  const int steps = (bi + 1) * 2;               // K-steps of 64 elems
  const int W = (steps + nc - 1) / nc;
  const int s0 = ck * W;
  const int s1 = min(s0 + W, steps);
  if (s0 >= s1) return;

  GEMM_PREAMBLE();
  const int brow = bi * 128, bcol = bj * 128;
  GEMM_LOOP(P + (size_t)brow * SEQQ, SEQQ, Vt + (size_t)bcol * SEQQ, SEQQ, s0, s1);
  const int c0 = wc + (lane & 15);
  const int r0 = wr + ((lane >> 4) << 2);
  if (ck == 0) {
#pragma unroll
    for (int m = 0; m < 4; ++m) {
      const int r = brow + r0 + m * 16;
#pragma unroll
      for (int n = 0; n < 4; ++n) {
        const int c = bcol + c0 + n * 16;
#pragma unroll
        for (int j = 0; j < 4; ++j)
          O[(size_t)(r + j) * DDIM + c] = acc[m][n][j];
      }
    }
  } else {
    float* tile = part + ((size_t)(pv_rcbase(bi) + (ck - 1)) * 8 + bj) * 16384;
#pragma unroll
    for (int m = 0; m < 4; ++m) {
      const int lr = r0 + m * 16;
#pragma unroll
      for (int n = 0; n < 4; ++n) {
        const int lc = c0 + n * 16;
#pragma unroll
        for (int j = 0; j < 4; ++j)
          tile[(lr + j) * 128 + lc] = acc[m][n][j];
      }
    }
  }
}

// ---- add partial tiles into out rows >= 1024 ----
__global__ __launch_bounds__(256) void reduce_pv(float* __restrict__ O,
                                                 const float* __restrict__ part) {
  const int idx = blockIdx.x * 256 + threadIdx.x;   // one float4 per thread
  const int r = 1024 + (idx >> 8);                  // 256 float4s per row
  const int cc = (idx & 255) * 4;
  const int bi = r >> 7;
  const int nparts = pv_nc(bi) - 1;
  const int rcb = pv_rcbase(bi);
  const int bj = cc >> 7;
  const int lr = r & 127, lc = cc & 127;
  float4 acc = *reinterpret_cast<float4*>(O + (size_t)r * DDIM + cc);
  for (int k = 0; k < nparts; ++k) {
    const float4 p = *reinterpret_cast<const float4*>(
        part + ((size_t)(rcb + k) * 8 + bj) * 16384 + lr * 128 + lc);
    acc.x += p.x; acc.y += p.y; acc.z += p.z; acc.w += p.w;
  }
  *reinterpret_cast<float4*>(O + (size_t)r * DDIM + cc) = acc;
}

extern "C" void kernel_launch(void* const* d_in, const int* in_sizes, int n_in,
                              void* d_out, int out_size, void* d_ws, size_t ws_size,
                              hipStream_t stream) {
  (void)in_sizes; (void)n_in; (void)out_size; (void)ws_size;
  const float* x = (const float*)d_in[0];
  const float* Wq = (const float*)d_in[1];
  const float* Wk = (const float*)d_in[2];
  const float* Wv = (const float*)d_in[3];
  float* out = (float*)d_out;

  char* ws = (char*)d_ws;
  unsigned short* xb   = (unsigned short*)(ws);                        //  8 MB [4096,1024]
  unsigned short* Wcat = (unsigned short*)(ws + ((size_t)8 << 20));    //  6 MB [3072,1024]
  unsigned short* Qb   = (unsigned short*)(ws + ((size_t)14 << 20));   //  8 MB [4096,1024]
  unsigned short* Kb   = (unsigned short*)(ws + ((size_t)22 << 20));   //  8 MB [4096,1024]
  unsigned short* Vt   = (unsigned short*)(ws + ((size_t)30 << 20));   //  8 MB [1024,4096]
  unsigned short* S    = (unsigned short*)(ws + ((size_t)38 << 20));   // 32 MB [4096,4096]
  float* part = (float*)ws;  // 24 MB of partial tiles; reuses dead xb/Wcat/Qb/Kb region

  cvt_all<<<7168, 256, 0, stream>>>(x, Wq, Wk, Wv, xb, Wcat);
  gemm_qkv<<<dim3(24, 32), 256, 0, stream>>>(xb, Wcat, Qb, Kb, Vt);
  gemm_qkt<<<dim3(32, 32), 256, 0, stream>>>(Qb, Kb, S);
  softmax_causal<<<SEQQ, 256, 0, stream>>>(S);
  gemm_pv_split<<<dim3(8, 32, 4), 256, 0, stream>>>(S, Vt, out, part);
  reduce_pv<<<3072, 256, 0, stream>>>(out, part);
}

// Round 5
// 133.966 us; speedup vs baseline: 1.5369x; 1.1336x over previous
//
#include <hip/hip_runtime.h>
#include <hip/hip_bf16.h>
#include <cstdint>
#include <cstddef>

// SelfAttentionV2: x[4096,1024] fp32; Wq/Wk/Wv [1024,1024] fp32.
// out = softmax(causal((x Wq^T)(x Wk^T)^T / 32)) @ (x Wv^T), fp32 out.
//
// Pipeline (all bf16 MFMA):
//   cvt_all:  x->xb bf16, W->Wcat bf16 (Wq scaled by 1/32), one fused launch
//   gemm_qkv: C[4096,3072] = xb @ Wcat^T -> Qb,Kb row-major bf16; V transposed (Vt[1024][4096])
//   gemm_qkt: S = Qb @ Kb^T, lower-triangle tiles only, diag masked with -inf, bf16
//   softmax:  row softmax over causal prefix, in place, bf16 P
//   gemm_pv_split: out = P @ Vt^T, split-K; chunk0 -> out, chunks>=1 -> fp32 partials
//   reduce_pv: out[rows>=1024] += partials
//
// GEMM main loop: 128x128 tile, BK=64, DOUBLE-buffered LDS (64KB -> 2 blocks/CU),
// T4 counted vmcnt: issue next step's 8 global_load_lds into buf^1, then wait
// vmcnt(8) (oldest 8 = current buffer complete) -> the new loads overlap the
// current step's ds_read+MFMA. Never vmcnt(0) in steady state.
// LDS rows are 128B => XOR swizzle byte ^= ((row&7)<<4), applied to the
// global SOURCE on stage (global_load_lds writes linearly) and to the
// ds_read address (same involution both sides).

#define SEQQ 4096
#define DDIM 1024

typedef __bf16 bf16x8 __attribute__((ext_vector_type(8)));
typedef float f32x4 __attribute__((ext_vector_type(4)));

__device__ __forceinline__ unsigned short f2bf(float f) {
  unsigned int u = __builtin_bit_cast(unsigned int, f);
  unsigned int r = u + 0x7FFFu + ((u >> 16) & 1u);  // RNE; -inf stays -inf
  return (unsigned short)(r >> 16);
}

__device__ __forceinline__ void gload_lds16(const void* g, void* lds) {
  __builtin_amdgcn_global_load_lds(
      (__attribute__((address_space(1))) void*)(uintptr_t)g,
      (__attribute__((address_space(3))) void*)(uintptr_t)lds, 16, 0, 0);
}

// ---- fused fp32 -> bf16 conversion (x, Wq*1/32, Wk, Wv) ----
__global__ __launch_bounds__(256) void cvt_all(const float* __restrict__ x,
                                               const float* __restrict__ Wq,
                                               const float* __restrict__ Wk,
                                               const float* __restrict__ Wv,
                                               unsigned short* __restrict__ xb,
                                               unsigned short* __restrict__ Wcat) {
  int b = blockIdx.x;
  const float* src;
  unsigned short* dst;
  float scale = 1.0f;
  if (b < 4096) {
    src = x; dst = xb;
  } else if (b < 5120) {
    src = Wq; dst = Wcat; scale = 0.03125f; b -= 4096;
  } else if (b < 6144) {
    src = Wk; dst = Wcat + (1u << 20); b -= 5120;
  } else {
    src = Wv; dst = Wcat + (2u << 20); b -= 6144;
  }
  const int i = (b * 256 + threadIdx.x) * 4;
  const float4 v = *reinterpret_cast<const float4*>(src + i);
  ushort4 o;
  o.x = f2bf(v.x * scale);
  o.y = f2bf(v.y * scale);
  o.z = f2bf(v.z * scale);
  o.w = f2bf(v.w * scale);
  *reinterpret_cast<ushort4*>(dst + i) = o;
}

// ---- GEMM building blocks: 128x128 tile, BK=64, 4 waves, 2x LDS buffers ----
// LDS tile [128][64] bf16 (128B rows). Stage: 16 chunks of 1KB (8 rows each);
// chunk c = i*4+wave, lane l writes row c*8 + l/8, colb (l&7)*16, with the
// source column pre-XORed by ((row&7)<<4) = ((l>>3)<<4).

__device__ __forceinline__ void stage_init(const unsigned short* gtile, size_t ld,
                                           const char* p[4], int wave, int lane) {
  const int lrow = lane >> 3;                                 // 0..7 = row&7
  const int colb = ((lane & 7) * 16) ^ (lrow << 4);           // inverse-swizzled source
#pragma unroll
  for (int i = 0; i < 4; ++i) {
    const int row = (i * 4 + wave) * 8 + lrow;
    p[i] = (const char*)gtile + (size_t)row * (ld * 2) + colb;
  }
}

__device__ __forceinline__ void stage_issue(const char* p[4], unsigned short* lds, int wave) {
#pragma unroll
  for (int i = 0; i < 4; ++i)
    gload_lds16(p[i], (char*)lds + (i * 4 + wave) * 1024);
}

// Precompute the 8 swizzled frag addresses per operand (m=0..3, kk=0..1),
// relative to buffer 0; buffer 1 adds +8192 elems (16KB).
__device__ __forceinline__ void frag_addrs(const unsigned short* lds, int wrow, int lane,
                                           const unsigned short* fa[4][2]) {
  const int rbase = wrow + (lane & 15);
  const int cb = (lane >> 4) * 16;
#pragma unroll
  for (int m = 0; m < 4; ++m) {
    const int r = rbase + m * 16;
    const int sw = (r & 7) << 4;
    fa[m][0] = (const unsigned short*)((const char*)lds + r * 128 + (cb ^ sw));
    fa[m][1] = (const unsigned short*)((const char*)lds + r * 128 + ((64 + cb) ^ sw));
  }
}

#define GEMM_PREAMBLE()                                                     \
  __shared__ unsigned short As[2][8192] __attribute__((aligned(16)));       \
  __shared__ unsigned short Bs[2][8192] __attribute__((aligned(16)));       \
  const int tid = threadIdx.x;                                              \
  const int wave = tid >> 6, lane = tid & 63;                               \
  const int wr = (wave >> 1) * 64, wc = (wave & 1) * 64;                    \
  f32x4 acc[4][4] = {};

// K loop over BK=64 steps [S0,S1); step s covers elems [s*64, s*64+64).
// 2-deep pipeline, counted vmcnt(8) in steady state.
#define GEMM_LOOP(ABASE, LDA, BBASE, LDB, S0, S1)                           \
  do {                                                                      \
    const char* pa[4];                                                      \
    const char* pb[4];                                                      \
    stage_init((ABASE) + (size_t)(S0) * 64, (LDA), pa, wave, lane);         \
    stage_init((BBASE) + (size_t)(S0) * 64, (LDB), pb, wave, lane);         \
    const unsigned short* fa[4][2];                                         \
    const unsigned short* fb[4][2];                                         \
    frag_addrs(As[0], wr, lane, fa);                                        \
    frag_addrs(Bs[0], wc, lane, fb);                                        \
    stage_issue(pa, As[0], wave);                                           \
    stage_issue(pb, Bs[0], wave);                                           \
    int cur = 0;                                                            \
    for (int s = (S0); s < (S1); ++s) {                                     \
      _Pragma("unroll")                                                     \
      for (int i = 0; i < 4; ++i) { pa[i] += 128; pb[i] += 128; }           \
      if (s + 1 < (S1)) {                                                   \
        stage_issue(pa, As[cur ^ 1], wave);                                 \
        stage_issue(pb, Bs[cur ^ 1], wave);                                 \
        asm volatile("s_waitcnt vmcnt(8)" ::: "memory");                    \
      } else {                                                              \
        asm volatile("s_waitcnt vmcnt(0)" ::: "memory");                    \
      }                                                                     \
      asm volatile("s_barrier" ::: "memory");                               \
      const int off = cur ? 8192 : 0;                                       \
      bf16x8 a[4][2], b[4][2];                                              \
      _Pragma("unroll")                                                     \
      for (int m = 0; m < 4; ++m) {                                         \
        a[m][0] = *reinterpret_cast<const bf16x8*>(fa[m][0] + off);         \
        a[m][1] = *reinterpret_cast<const bf16x8*>(fa[m][1] + off);         \
        b[m][0] = *reinterpret_cast<const bf16x8*>(fb[m][0] + off);         \
        b[m][1] = *reinterpret_cast<const bf16x8*>(fb[m][1] + off);         \
      }                                                                     \
      _Pragma("unroll")                                                     \
      for (int kk = 0; kk < 2; ++kk)                                        \
        _Pragma("unroll")                                                   \
        for (int m = 0; m < 4; ++m)                                         \
          _Pragma("unroll")                                                 \
          for (int n = 0; n < 4; ++n)                                       \
            acc[m][n] = __builtin_amdgcn_mfma_f32_16x16x32_bf16(            \
                a[m][kk], b[n][kk], acc[m][n], 0, 0, 0);                    \
      asm volatile("s_waitcnt lgkmcnt(0)" ::: "memory");                    \
      asm volatile("s_barrier" ::: "memory");                               \
      cur ^= 1;                                                             \
    }                                                                       \
  } while (0)

// ---- QKV: C[4096,3072] = xb @ Wcat^T; Q,K row-major; V transposed ----
__global__ __launch_bounds__(256) void gemm_qkv(const unsigned short* __restrict__ X,
                                                const unsigned short* __restrict__ W,
                                                unsigned short* __restrict__ Qb,
                                                unsigned short* __restrict__ Kb,
                                                unsigned short* __restrict__ Vt) {
  GEMM_PREAMBLE();
  const int brow = blockIdx.y * 128, bcol = blockIdx.x * 128;
  GEMM_LOOP(X + (size_t)brow * DDIM, DDIM, W + (size_t)bcol * DDIM, DDIM, 0, 16);
  const int region = bcol >> 10;  // 0=Q 1=K 2=V
  const int lcol = bcol & 1023;
  const int c0 = wc + (lane & 15);
  const int r0 = wr + ((lane >> 4) << 2);
  if (region < 2) {
    unsigned short* dst = (region == 0) ? Qb : Kb;
#pragma unroll
    for (int m = 0; m < 4; ++m) {
      const int r = brow + r0 + m * 16;
#pragma unroll
      for (int n = 0; n < 4; ++n) {
        const int c = lcol + c0 + n * 16;
#pragma unroll
        for (int j = 0; j < 4; ++j)
          dst[(size_t)(r + j) * DDIM + c] = f2bf(acc[m][n][j]);
      }
    }
  } else {
#pragma unroll
    for (int m = 0; m < 4; ++m) {
      const int r = brow + r0 + m * 16;
#pragma unroll
      for (int n = 0; n < 4; ++n) {
        const int c = lcol + c0 + n * 16;
        ushort4 pk;
        pk.x = f2bf(acc[m][n][0]);
        pk.y = f2bf(acc[m][n][1]);
        pk.z = f2bf(acc[m][n][2]);
        pk.w = f2bf(acc[m][n][3]);
        *reinterpret_cast<ushort4*>(Vt + (size_t)c * SEQQ + r) = pk;
      }
    }
  }
}

// ---- QK^T: S = Qb @ Kb^T, lower-triangle tiles, causal mask on diag ----
__global__ __launch_bounds__(256) void gemm_qkt(const unsigned short* __restrict__ Qb,
                                                const unsigned short* __restrict__ Kb,
                                                unsigned short* __restrict__ S) {
  const int bi = blockIdx.y, bj = blockIdx.x;
  if (bj > bi) return;  // upper-triangle tiles never computed nor read
  GEMM_PREAMBLE();
  const int brow = bi * 128, bcol = bj * 128;
  GEMM_LOOP(Qb + (size_t)brow * DDIM, DDIM, Kb + (size_t)bcol * DDIM, DDIM, 0, 16);
  const int c0 = wc + (lane & 15);
  const int r0 = wr + ((lane >> 4) << 2);
#pragma unroll
  for (int m = 0; m < 4; ++m) {
    const int r = brow + r0 + m * 16;
#pragma unroll
    for (int n = 0; n < 4; ++n) {
      const int c = bcol + c0 + n * 16;
#pragma unroll
      for (int j = 0; j < 4; ++j) {
        unsigned short o = (c > r + j) ? (unsigned short)0xFF80  // -inf bf16
                                       : f2bf(acc[m][n][j]);
        S[(size_t)(r + j) * SEQQ + c] = o;
      }
    }
  }
}

// ---- row softmax over causal prefix, in place ----
__global__ __launch_bounds__(256) void softmax_causal(unsigned short* __restrict__ S) {
  const int row = blockIdx.x;
  const int L = ((row >> 7) + 1) << 7;  // multiple of 128 covering row+1
  unsigned short* Srow = S + (size_t)row * SEQQ;
  __shared__ float red[4];
  const int tid = threadIdx.x;
  const int lane = tid & 63, wave = tid >> 6;

  float x[16];
  bool have[2];
  float m = -3.0e38f;
#pragma unroll
  for (int it = 0; it < 2; ++it) {
    const int j = tid * 8 + it * 2048;
    have[it] = (j < L);
    if (have[it]) {
      const uint4 v = *reinterpret_cast<const uint4*>(Srow + j);
      const unsigned u[4] = {v.x, v.y, v.z, v.w};
#pragma unroll
      for (int q = 0; q < 4; ++q) {
        x[it * 8 + q * 2] = __builtin_bit_cast(float, u[q] << 16);
        x[it * 8 + q * 2 + 1] = __builtin_bit_cast(float, u[q] & 0xFFFF0000u);
      }
#pragma unroll
      for (int q = 0; q < 8; ++q) m = fmaxf(m, x[it * 8 + q]);
    }
  }
#pragma unroll
  for (int o = 32; o; o >>= 1) m = fmaxf(m, __shfl_xor(m, o));
  if (lane == 0) red[wave] = m;
  __syncthreads();
  m = fmaxf(fmaxf(red[0], red[1]), fmaxf(red[2], red[3]));
  __syncthreads();

  float sum = 0.f;
#pragma unroll
  for (int it = 0; it < 2; ++it)
    if (have[it]) {
#pragma unroll
      for (int q = 0; q < 8; ++q) {
        x[it * 8 + q] = __expf(x[it * 8 + q] - m);  // exp(-inf)=0 for masked
        sum += x[it * 8 + q];
      }
    }
#pragma unroll
  for (int o = 32; o; o >>= 1) sum += __shfl_xor(sum, o);
  if (lane == 0) red[wave] = sum;
  __syncthreads();
  sum = red[0] + red[1] + red[2] + red[3];
  const float inv = 1.0f / sum;

#pragma unroll
  for (int it = 0; it < 2; ++it)
    if (have[it]) {
      const int j = tid * 8 + it * 2048;
      unsigned u[4];
#pragma unroll
      for (int q = 0; q < 4; ++q) {
        u[q] = (unsigned)f2bf(x[it * 8 + q * 2] * inv) |
               ((unsigned)f2bf(x[it * 8 + q * 2 + 1] * inv) << 16);
      }
      *reinterpret_cast<uint4*>(Srow + j) = make_uint4(u[0], u[1], u[2], u[3]);
    }
}

// ---- partial-tile index helpers for split-K PV ----
// nc(bi) = (bi>>3)+1 chunks. Chunk 0 -> direct to out; chunks c>=1 -> partial
// tile rc = rcBase(bi) + (c-1), 8 bj tiles per rc, 64KB fp32 each.
__device__ __forceinline__ int pv_nc(int bi) { return (bi >> 3) + 1; }
__device__ __forceinline__ int pv_rcbase(int bi) {
  const int g = bi >> 3;  // 1..3 for bi>=8
  return (g == 1) ? (bi - 8) : (g == 2) ? 8 + (bi - 16) * 2 : 24 + (bi - 24) * 3;
}

// ---- PV split-K: out/partials = P @ Vt^T ----
__global__ __launch_bounds__(256) void gemm_pv_split(const unsigned short* __restrict__ P,
                                                     const unsigned short* __restrict__ Vt,
                                                     float* __restrict__ O,
                                                     float* __restrict__ part) {
  const int bj = blockIdx.x, bi = blockIdx.y, ck = blockIdx.z;
  const int nc = pv_nc(bi);
  if (ck >= nc) return;
  const int steps = (bi + 1) * 2;               // K-steps of 64 elems
  const int W = (steps + nc - 1) / nc;
  const int s0 = ck * W;
  const int s1 = min(s0 + W, steps);
  if (s0 >= s1) return;

  GEMM_PREAMBLE();
  const int brow = bi * 128, bcol = bj * 128;
  GEMM_LOOP(P + (size_t)brow * SEQQ, SEQQ, Vt + (size_t)bcol * SEQQ, SEQQ, s0, s1);
  const int c0 = wc + (lane & 15);
  const int r0 = wr + ((lane >> 4) << 2);
  if (ck == 0) {
#pragma unroll
    for (int m = 0; m < 4; ++m) {
      const int r = brow + r0 + m * 16;
#pragma unroll
      for (int n = 0; n < 4; ++n) {
        const int c = bcol + c0 + n * 16;
#pragma unroll
        for (int j = 0; j < 4; ++j)
          O[(size_t)(r + j) * DDIM + c] = acc[m][n][j];
      }
    }
  } else {
    float* tile = part + ((size_t)(pv_rcbase(bi) + (ck - 1)) * 8 + bj) * 16384;
#pragma unroll
    for (int m = 0; m < 4; ++m) {
      const int lr = r0 + m * 16;
#pragma unroll
      for (int n = 0; n < 4; ++n) {
        const int lc = c0 + n * 16;
#pragma unroll
        for (int j = 0; j < 4; ++j)
          tile[(lr + j) * 128 + lc] = acc[m][n][j];
      }
    }
  }
}

// ---- add partial tiles into out rows >= 1024 ----
__global__ __launch_bounds__(256) void reduce_pv(float* __restrict__ O,
                                                 const float* __restrict__ part) {
  const int idx = blockIdx.x * 256 + threadIdx.x;   // one float4 per thread
  const int r = 1024 + (idx >> 8);                  // 256 float4s per row
  const int cc = (idx & 255) * 4;
  const int bi = r >> 7;
  const int nparts = pv_nc(bi) - 1;
  const int rcb = pv_rcbase(bi);
  const int bj = cc >> 7;
  const int lr = r & 127, lc = cc & 127;
  float4 acc = *reinterpret_cast<float4*>(O + (size_t)r * DDIM + cc);
  for (int k = 0; k < nparts; ++k) {
    const float4 p = *reinterpret_cast<const float4*>(
        part + ((size_t)(rcb + k) * 8 + bj) * 16384 + lr * 128 + lc);
    acc.x += p.x; acc.y += p.y; acc.z += p.z; acc.w += p.w;
  }
  *reinterpret_cast<float4*>(O + (size_t)r * DDIM + cc) = acc;
}

extern "C" void kernel_launch(void* const* d_in, const int* in_sizes, int n_in,
                              void* d_out, int out_size, void* d_ws, size_t ws_size,
                              hipStream_t stream) {
  (void)in_sizes; (void)n_in; (void)out_size; (void)ws_size;
  const float* x = (const float*)d_in[0];
  const float* Wq = (const float*)d_in[1];
  const float* Wk = (const float*)d_in[2];
  const float* Wv = (const float*)d_in[3];
  float* out = (float*)d_out;

  char* ws = (char*)d_ws;
  unsigned short* xb   = (unsigned short*)(ws);                        //  8 MB [4096,1024]
  unsigned short* Wcat = (unsigned short*)(ws + ((size_t)8 << 20));    //  6 MB [3072,1024]
  unsigned short* Qb   = (unsigned short*)(ws + ((size_t)14 << 20));   //  8 MB [4096,1024]
  unsigned short* Kb   = (unsigned short*)(ws + ((size_t)22 << 20));   //  8 MB [4096,1024]
  unsigned short* Vt   = (unsigned short*)(ws + ((size_t)30 << 20));   //  8 MB [1024,4096]
  unsigned short* S    = (unsigned short*)(ws + ((size_t)38 << 20));   // 32 MB [4096,4096]
  float* part = (float*)ws;  // 24 MB of partial tiles; reuses dead xb/Wcat/Qb/Kb region

  cvt_all<<<7168, 256, 0, stream>>>(x, Wq, Wk, Wv, xb, Wcat);
  gemm_qkv<<<dim3(24, 32), 256, 0, stream>>>(xb, Wcat, Qb, Kb, Vt);
  gemm_qkt<<<dim3(32, 32), 256, 0, stream>>>(Qb, Kb, S);
  softmax_causal<<<SEQQ, 256, 0, stream>>>(S);
  gemm_pv_split<<<dim3(8, 32, 4), 256, 0, stream>>>(S, Vt, out, part);
  reduce_pv<<<3072, 256, 0, stream>>>(out, part);
}